// Round 1
// baseline (912.514 us; speedup 1.0000x reference)
//
#include <hip/hip_runtime.h>
#include <stdint.h>

#define B_    16
#define L_    2048
#define DIN_  1024
#define H_    512
#define NCOL_ 3072          // 2 * H * 3
#define M_    (B_ * L_)     // 32768
#define K_    DIN_          // 1024

typedef unsigned short u16;
typedef __bf16 bf16_t;
typedef bf16_t bf16x8 __attribute__((ext_vector_type(8)));
typedef float  f32x4  __attribute__((ext_vector_type(4)));

__device__ __forceinline__ u16 f2bf(float f) {
  union { float f; uint32_t u; } v; v.f = f;
  return (u16)((v.u + 0x7fffu + ((v.u >> 16) & 1u)) >> 16);  // RNE
}
__device__ __forceinline__ float bf2f(u16 b) {
  union { uint32_t u; float f; } v; v.u = ((uint32_t)b) << 16; return v.f;
}

// ---------------- x f32 -> bf16 ----------------
__global__ void cvt_x_kernel(const float4* __restrict__ x, ushort4* __restrict__ xb) {
  int i = blockIdx.x * blockDim.x + threadIdx.x;   // exact grid, no bounds
  float4 v = x[i];
  ushort4 o;
  o.x = f2bf(v.x); o.y = f2bf(v.y); o.z = f2bf(v.z); o.w = f2bf(v.w);
  xb[i] = o;
}

// ---------------- W (K x N) -> Wt (N x K) bf16 ----------------
__global__ void transpose_w_kernel(const float* __restrict__ W, u16* __restrict__ Wt) {
  __shared__ float s[32][33];
  int n0 = blockIdx.x * 32;   // N tile
  int i0 = blockIdx.y * 32;   // K tile
  int tx = threadIdx.x, ty = threadIdx.y;  // (32, 8)
  #pragma unroll
  for (int y = 0; y < 32; y += 8)
    s[ty + y][tx] = W[(uint64_t)(i0 + ty + y) * NCOL_ + n0 + tx];
  __syncthreads();
  #pragma unroll
  for (int y = 0; y < 32; y += 8)
    Wt[(uint64_t)(n0 + ty + y) * K_ + i0 + tx] = f2bf(s[tx][ty + y]);
}

// ---------------- GEMM: U[m][n] = sum_k A[m][k] * Wt[n][k], bf16 MFMA ----------------
__device__ __forceinline__ void gload_lds16(const void* g, void* lds) {
  __builtin_amdgcn_global_load_lds(
      (const __attribute__((address_space(1))) uint32_t*)g,
      (__attribute__((address_space(3))) uint32_t*)lds, 16, 0, 0);
}

__global__ __launch_bounds__(256) void gemm_u_kernel(const u16* __restrict__ A,
                                                     const u16* __restrict__ Bt,
                                                     u16* __restrict__ U) {
  __shared__ __align__(16) u16 As[128 * 32];
  __shared__ __align__(16) u16 Bs[128 * 32];
  const int bid  = blockIdx.x;
  const int bn   = bid % (NCOL_ / 128);
  const int bm   = bid / (NCOL_ / 128);
  const int m0   = bm * 128, n0 = bn * 128;
  const int tid  = threadIdx.x;
  const int w    = tid >> 6, lane = tid & 63;
  const int wr   = w >> 1, wc = w & 1;
  const int r    = lane & 15, half = lane >> 4;

  f32x4 acc[4][4] = {};

  const int jBase  = w * 2;
  const int rowSub = lane >> 2;        // 0..15 within chunk
  const int colOff = (lane & 3) * 8;   // u16 elems within 32-elem row

  for (int kt = 0; kt < K_; kt += 32) {
    __syncthreads();
    #pragma unroll
    for (int c0 = 0; c0 < 2; ++c0) {
      int j = jBase + c0;              // chunk 0..7, 1024 B each
      gload_lds16(A  + (uint64_t)(m0 + j * 16 + rowSub) * K_ + kt + colOff,
                  (char*)As + j * 1024);
      gload_lds16(Bt + (uint64_t)(n0 + j * 16 + rowSub) * K_ + kt + colOff,
                  (char*)Bs + j * 1024);
    }
    __syncthreads();

    bf16x8 af[4], bfr[4];
    #pragma unroll
    for (int mi = 0; mi < 4; ++mi) {
      int row = wr * 64 + mi * 16 + r;
      af[mi] = __builtin_bit_cast(bf16x8, *(const f32x4*)(&As[row * 32 + half * 8]));
    }
    #pragma unroll
    for (int ni = 0; ni < 4; ++ni) {
      int row = wc * 64 + ni * 16 + r;
      bfr[ni] = __builtin_bit_cast(bf16x8, *(const f32x4*)(&Bs[row * 32 + half * 8]));
    }
    #pragma unroll
    for (int mi = 0; mi < 4; ++mi)
      #pragma unroll
      for (int ni = 0; ni < 4; ++ni)
        acc[mi][ni] = __builtin_amdgcn_mfma_f32_16x16x32_bf16(af[mi], bfr[ni], acc[mi][ni], 0, 0, 0);
  }

  // epilogue: C/D layout col = lane&15, row = (lane>>4)*4 + i   [m89-verified]
  #pragma unroll
  for (int mi = 0; mi < 4; ++mi) {
    #pragma unroll
    for (int ni = 0; ni < 4; ++ni) {
      int col = n0 + wc * 64 + ni * 16 + r;
      #pragma unroll
      for (int i = 0; i < 4; ++i) {
        int row = m0 + wr * 64 + mi * 16 + half * 4 + i;
        U[(uint64_t)row * NCOL_ + col] = f2bf(acc[mi][ni][i]);
      }
    }
  }
}

// ---------------- sequential scan: one thread per (b, dir, h) ----------------
__global__ void sru_scan_kernel(const float* __restrict__ x, const u16* __restrict__ U,
                                const float* __restrict__ bfp, const float* __restrict__ brp,
                                float* __restrict__ outh, float* __restrict__ outc) {
  int tid = blockIdx.x * blockDim.x + threadIdx.x;  // 0..16383
  int b  = tid >> 10;
  int ch = tid & 1023;          // d*512 + h
  int d  = ch >> 9;
  float bfv = bfp[ch], brv = brp[ch];
  const u16*   Ub = U + (uint64_t)b * L_ * NCOL_ + (uint64_t)(ch >> 9) * 1536 + (uint64_t)(ch & 511) * 3;
  const float* xb = x + (uint64_t)b * L_ * DIN_ + ch;
  float*       hb = outh + (uint64_t)b * L_ * DIN_ + ch;

  float c = 0.f;
  const int stepd = d ? -1 : 1;
  int l = d ? (L_ - 1) : 0;
  #pragma unroll 4
  for (int it = 0; it < L_; ++it, l += stepd) {
    const u16* up = Ub + (uint64_t)l * NCOL_;
    float xtil = bf2f(up[0]);
    float fpre = bf2f(up[1]);
    float rpre = bf2f(up[2]);
    float xres = xb[(uint64_t)l * DIN_];
    float f  = 1.f / (1.f + __expf(-(fpre + bfv)));
    float rr = 1.f / (1.f + __expf(-(rpre + brv)));
    c = f * c + (1.f - f) * xtil;
    float th = 1.f - 2.f / (__expf(2.f * c) + 1.f);   // tanh, saturates correctly
    hb[(uint64_t)l * DIN_] = rr * th + (1.f - rr) * xres;
  }
  outc[ch * B_ + b] = c;   // c.T layout (2H, B)
}

// ---------------- launch ----------------
extern "C" void kernel_launch(void* const* d_in, const int* in_sizes, int n_in,
                              void* d_out, int out_size, void* d_ws, size_t ws_size,
                              hipStream_t stream) {
  const float* x   = (const float*)d_in[0];
  const float* W   = (const float*)d_in[1];
  const float* bfp = (const float*)d_in[2];
  const float* brp = (const float*)d_in[3];

  float* outh = (float*)d_out;
  float* outc = outh + (size_t)B_ * L_ * DIN_;   // after (B, L, 2H)

  u16* xb = (u16*)d_ws;                          // M_*K_ bf16        = 64 MiB
  u16* Wt = xb + (size_t)M_ * K_;                // NCOL_*K_ bf16     = 6 MiB
  u16* U  = Wt + (size_t)NCOL_ * K_;             // M_*NCOL_ bf16     = 192 MiB

  cvt_x_kernel<<<(M_ * K_ / 4) / 256, 256, 0, stream>>>((const float4*)x, (ushort4*)xb);
  transpose_w_kernel<<<dim3(NCOL_ / 32, K_ / 32), dim3(32, 8), 0, stream>>>(W, Wt);
  gemm_u_kernel<<<(M_ / 128) * (NCOL_ / 128), 256, 0, stream>>>(xb, Wt, U);
  sru_scan_kernel<<<M_ * NCOL_ ? (B_ * 2 * H_) / 64 : 0, 64, 0, stream>>>(x, U, bfp, brp, outh, outc);
}

// Round 2
// 602.830 us; speedup vs baseline: 1.5137x; 1.5137x over previous
//
#include <hip/hip_runtime.h>
#include <stdint.h>

#define B_    16
#define L_    2048
#define DIN_  1024
#define H_    512
#define NCOL_ 3072          // 2 * H * 3
#define M_    (B_ * L_)     // 32768
#define K_    DIN_          // 1024
#define NCHUNK 16
#define CHUNK  128          // L_ / NCHUNK

typedef unsigned short u16;
typedef __bf16 bf16_t;
typedef bf16_t bf16x8 __attribute__((ext_vector_type(8)));
typedef float  f32x4  __attribute__((ext_vector_type(4)));

__device__ __forceinline__ u16 f2bf(float f) {
  union { float f; uint32_t u; } v; v.f = f;
  return (u16)((v.u + 0x7fffu + ((v.u >> 16) & 1u)) >> 16);  // RNE
}
__device__ __forceinline__ u16 f2h(float f) {
  _Float16 h = (_Float16)f; return *(u16*)&h;
}
__device__ __forceinline__ float h2f(u16 b) {
  _Float16 h = *(_Float16*)&b; return (float)h;
}

// ---------------- x f32 -> bf16 ----------------
__global__ void cvt_x_kernel(const float4* __restrict__ x, ushort4* __restrict__ xb) {
  int i = blockIdx.x * blockDim.x + threadIdx.x;   // exact grid, no bounds
  float4 v = x[i];
  ushort4 o;
  o.x = f2bf(v.x); o.y = f2bf(v.y); o.z = f2bf(v.z); o.w = f2bf(v.w);
  xb[i] = o;
}

// ---------------- W (K x N) -> Wt (N x K) bf16 ----------------
__global__ void transpose_w_kernel(const float* __restrict__ W, u16* __restrict__ Wt) {
  __shared__ float s[32][33];
  int n0 = blockIdx.x * 32;   // N tile
  int i0 = blockIdx.y * 32;   // K tile
  int tx = threadIdx.x, ty = threadIdx.y;  // (32, 8)
  #pragma unroll
  for (int y = 0; y < 32; y += 8)
    s[ty + y][tx] = W[(uint64_t)(i0 + ty + y) * NCOL_ + n0 + tx];
  __syncthreads();
  #pragma unroll
  for (int y = 0; y < 32; y += 8)
    Wt[(uint64_t)(n0 + ty + y) * K_ + i0 + tx] = f2bf(s[tx][ty + y]);
}

// ---------------- GEMM: U = A (M,K) * Wt^T, bf16 MFMA; epilogue -> 3 fp16 planes ----------------
__device__ __forceinline__ void gload_lds16(const void* g, void* lds) {
  __builtin_amdgcn_global_load_lds(
      (const __attribute__((address_space(1))) uint32_t*)g,
      (__attribute__((address_space(3))) uint32_t*)lds, 16, 0, 0);
}

__global__ __launch_bounds__(256) void gemm_u_kernel(const u16* __restrict__ A,
                                                     const u16* __restrict__ Bt,
                                                     const float* __restrict__ bfp,
                                                     const float* __restrict__ brp,
                                                     u16* __restrict__ xtilP,
                                                     u16* __restrict__ fP,
                                                     u16* __restrict__ rP) {
  __shared__ __align__(16) u16 As[128 * 32];
  __shared__ __align__(16) u16 Bs[128 * 32];
  const int bid  = blockIdx.x;
  const int bn   = bid % (NCOL_ / 128);
  const int bm   = bid / (NCOL_ / 128);
  const int m0   = bm * 128, n0 = bn * 128;
  const int tid  = threadIdx.x;
  const int w    = tid >> 6, lane = tid & 63;
  const int wr   = w >> 1, wc = w & 1;
  const int r    = lane & 15, half = lane >> 4;

  f32x4 acc[4][4] = {};

  const int jBase  = w * 2;
  const int rowSub = lane >> 2;        // 0..15 within chunk
  const int colOff = (lane & 3) * 8;   // u16 elems within 32-elem row

  for (int kt = 0; kt < K_; kt += 32) {
    __syncthreads();
    #pragma unroll
    for (int c0 = 0; c0 < 2; ++c0) {
      int j = jBase + c0;              // chunk 0..7, 1024 B each
      gload_lds16(A  + (uint64_t)(m0 + j * 16 + rowSub) * K_ + kt + colOff,
                  (char*)As + j * 1024);
      gload_lds16(Bt + (uint64_t)(n0 + j * 16 + rowSub) * K_ + kt + colOff,
                  (char*)Bs + j * 1024);
    }
    __syncthreads();

    bf16x8 af[4], bfr[4];
    #pragma unroll
    for (int mi = 0; mi < 4; ++mi) {
      int row = wr * 64 + mi * 16 + r;
      af[mi] = __builtin_bit_cast(bf16x8, *(const f32x4*)(&As[row * 32 + half * 8]));
    }
    #pragma unroll
    for (int ni = 0; ni < 4; ++ni) {
      int row = wc * 64 + ni * 16 + r;
      bfr[ni] = __builtin_bit_cast(bf16x8, *(const f32x4*)(&Bs[row * 32 + half * 8]));
    }
    #pragma unroll
    for (int mi = 0; mi < 4; ++mi)
      #pragma unroll
      for (int ni = 0; ni < 4; ++ni)
        acc[mi][ni] = __builtin_amdgcn_mfma_f32_16x16x32_bf16(af[mi], bfr[ni], acc[mi][ni], 0, 0, 0);
  }

  // epilogue: C/D layout col = lane&15, row = (lane>>4)*4 + i   [m89-verified]
  // col -> (d, h, k): col = d*1536 + h*3 + k.  Planes are [m][d*512+h], fp16.
  #pragma unroll
  for (int mi = 0; mi < 4; ++mi) {
    #pragma unroll
    for (int ni = 0; ni < 4; ++ni) {
      int col = n0 + wc * 64 + ni * 16 + r;
      int k   = col % 3;
      int d   = col / 1536;
      int hc  = (col % 1536) / 3;
      int ch  = d * 512 + hc;
      u16* plane = (k == 0) ? xtilP : (k == 1 ? fP : rP);
      float bias = (k == 0) ? 0.f : (k == 1 ? bfp[ch] : brp[ch]);
      #pragma unroll
      for (int i = 0; i < 4; ++i) {
        int row = m0 + wr * 64 + mi * 16 + half * 4 + i;
        float v = acc[mi][ni][i];
        if (k) v = 1.f / (1.f + __expf(-(v + bias)));   // pre-apply sigmoid for f,r
        plane[(uint64_t)row * 1024 + ch] = f2h(v);
      }
    }
  }
}

// ---------------- chunked scan, phase A: per-chunk partial (c0=0) + decay product ----------------
__global__ __launch_bounds__(256) void scan_partial_kernel(const u16* __restrict__ xtilP,
                                                           const u16* __restrict__ fP,
                                                           float* __restrict__ cpart,
                                                           float* __restrict__ Pp) {
  int tid = blockIdx.x * 256 + threadIdx.x;       // 262144 = B * NCHUNK * 1024
  int ch = tid & 1023, chunk = (tid >> 10) & (NCHUNK - 1), b = tid >> 14;
  int d = ch >> 9;
  int l = chunk * CHUNK + (d ? CHUNK - 1 : 0);
  int64_t stride = d ? -1024 : 1024;
  uint64_t base = ((uint64_t)b * L_ + l) * 1024 + ch;
  float c = 0.f, P = 1.f;
  #pragma unroll 4
  for (int it = 0; it < CHUNK; ++it) {
    float f  = h2f(fP[base]);
    float xt = h2f(xtilP[base]);
    c = f * c + (1.f - f) * xt;
    P *= f;
    base += stride;
  }
  int o = (b * NCHUNK + chunk) * 1024 + ch;
  cpart[o] = c;
  Pp[o] = P;
}

// ---------------- phase B: sequential combine across chunks (per channel) ----------------
__global__ void scan_combine_kernel(const float* __restrict__ cpart, const float* __restrict__ Pp,
                                    float* __restrict__ cin, float* __restrict__ outc) {
  int tid = blockIdx.x * blockDim.x + threadIdx.x;  // 16384
  int ch = tid & 1023, b = tid >> 10, d = ch >> 9;
  float c = 0.f;
  for (int i = 0; i < NCHUNK; ++i) {
    int chunk = d ? (NCHUNK - 1 - i) : i;
    int o = (b * NCHUNK + chunk) * 1024 + ch;
    cin[o] = c;
    c = cpart[o] + Pp[o] * c;
  }
  outc[ch * B_ + b] = c;   // c.T layout (2H, B)
}

// ---------------- phase C: re-scan each chunk from true c_in, emit h ----------------
__global__ __launch_bounds__(256) void scan_final_kernel(const float* __restrict__ x,
                                                         const u16* __restrict__ xtilP,
                                                         const u16* __restrict__ fP,
                                                         const u16* __restrict__ rP,
                                                         const float* __restrict__ cin,
                                                         float* __restrict__ outh) {
  int tid = blockIdx.x * 256 + threadIdx.x;       // 262144
  int ch = tid & 1023, chunk = (tid >> 10) & (NCHUNK - 1), b = tid >> 14;
  int d = ch >> 9;
  int l = chunk * CHUNK + (d ? CHUNK - 1 : 0);
  int64_t stride = d ? -1024 : 1024;
  uint64_t base = ((uint64_t)b * L_ + l) * 1024 + ch;
  float c = cin[(b * NCHUNK + chunk) * 1024 + ch];
  #pragma unroll 2
  for (int it = 0; it < CHUNK; ++it) {
    float f    = h2f(fP[base]);
    float xt   = h2f(xtilP[base]);
    float rr   = h2f(rP[base]);
    float xres = x[base];
    c = f * c + (1.f - f) * xt;
    float th = 1.f - 2.f / (__expf(2.f * c) + 1.f);   // tanh
    outh[base] = rr * th + (1.f - rr) * xres;
    base += stride;
  }
}

// ---------------- launch ----------------
extern "C" void kernel_launch(void* const* d_in, const int* in_sizes, int n_in,
                              void* d_out, int out_size, void* d_ws, size_t ws_size,
                              hipStream_t stream) {
  const float* x   = (const float*)d_in[0];
  const float* W   = (const float*)d_in[1];
  const float* bfp = (const float*)d_in[2];
  const float* brp = (const float*)d_in[3];

  float* outh = (float*)d_out;
  float* outc = outh + (size_t)B_ * L_ * DIN_;   // after (B, L, 2H)

  // ws layout (262 MiB total):
  u16* xb = (u16*)d_ws;                          // M_*K_ bf16      = 64 MiB (dead after GEMM)
  u16* Wt = xb + (size_t)M_ * K_;                // NCOL_*K_ bf16   = 6 MiB
  u16* xtilP = Wt + (size_t)NCOL_ * K_;          // M_*1024 fp16    = 64 MiB
  u16* fP    = xtilP + (size_t)M_ * 1024;        // 64 MiB
  u16* rP    = fP    + (size_t)M_ * 1024;        // 64 MiB
  // chunk-scan scratch aliases xb (GEMM completed before these run):
  float* cpart = (float*)d_ws;                   // B*NCHUNK*1024 f32 = 1 MiB
  float* Pp    = cpart + (size_t)B_ * NCHUNK * 1024;
  float* cin   = Pp    + (size_t)B_ * NCHUNK * 1024;

  cvt_x_kernel<<<(M_ * K_ / 4) / 256, 256, 0, stream>>>((const float4*)x, (ushort4*)xb);
  transpose_w_kernel<<<dim3(NCOL_ / 32, K_ / 32), dim3(32, 8), 0, stream>>>(W, Wt);
  gemm_u_kernel<<<(M_ / 128) * (NCOL_ / 128), 256, 0, stream>>>(xb, Wt, bfp, brp, xtilP, fP, rP);
  scan_partial_kernel<<<(B_ * NCHUNK * 1024) / 256, 256, 0, stream>>>(xtilP, fP, cpart, Pp);
  scan_combine_kernel<<<(B_ * 2 * H_) / 256, 256, 0, stream>>>(cpart, Pp, cin, outc);
  scan_final_kernel<<<(B_ * NCHUNK * 1024) / 256, 256, 0, stream>>>(x, xtilP, fP, rP, cin, outh);
}

// Round 3
// 495.960 us; speedup vs baseline: 1.8399x; 1.2155x over previous
//
#include <hip/hip_runtime.h>
#include <stdint.h>

#define B_    16
#define L_    2048
#define DIN_  1024
#define H_    512
#define NCOL_ 3072          // 2 * H * 3
#define M_    (B_ * L_)     // 32768
#define K_    DIN_          // 1024
#define NCHUNK 16
#define CHUNK  128          // L_ / NCHUNK

typedef unsigned short u16;
typedef __bf16 bf16_t;
typedef bf16_t bf16x8 __attribute__((ext_vector_type(8)));
typedef float  f32x4  __attribute__((ext_vector_type(4)));

__device__ __forceinline__ u16 f2bf(float f) {
  union { float f; uint32_t u; } v; v.f = f;
  return (u16)((v.u + 0x7fffu + ((v.u >> 16) & 1u)) >> 16);  // RNE
}
__device__ __forceinline__ float bf2f(u16 b) {
  union { uint32_t u; float f; } v; v.u = ((uint32_t)b) << 16; return v.f;
}
__device__ __forceinline__ u16 f2h(float f) {
  _Float16 h = (_Float16)f; return *(u16*)&h;
}
__device__ __forceinline__ float h2f(u16 b) {
  _Float16 h = *(_Float16*)&b; return (float)h;
}

// ---------------- x f32 -> bf16 ----------------
__global__ void cvt_x_kernel(const float4* __restrict__ x, ushort4* __restrict__ xb) {
  int i = blockIdx.x * blockDim.x + threadIdx.x;   // exact grid, no bounds
  float4 v = x[i];
  ushort4 o;
  o.x = f2bf(v.x); o.y = f2bf(v.y); o.z = f2bf(v.z); o.w = f2bf(v.w);
  xb[i] = o;
}

// ---------------- W (K x N) -> Wt (N' x K) bf16, rows plane-permuted ----------------
// n' = k*1024 + d*512 + h  (so the GEMM N axis is planar: [xtil | f | r])
__global__ void transpose_w_kernel(const float* __restrict__ W, u16* __restrict__ Wt) {
  __shared__ float s[32][33];
  int n0 = blockIdx.x * 32;   // N tile
  int i0 = blockIdx.y * 32;   // K tile
  int tx = threadIdx.x, ty = threadIdx.y;  // (32, 8)
  #pragma unroll
  for (int y = 0; y < 32; y += 8)
    s[ty + y][tx] = W[(uint64_t)(i0 + ty + y) * NCOL_ + n0 + tx];
  __syncthreads();
  #pragma unroll
  for (int y = 0; y < 32; y += 8) {
    int n = n0 + ty + y;
    int kk = n % 3, d = n / 1536, h = (n % 1536) / 3;
    int np = kk * 1024 + d * 512 + h;
    Wt[(uint64_t)np * K_ + i0 + tx] = f2bf(s[tx][ty + y]);
  }
}

// ---------------- GEMM: planar U epilogue (plane uniform per block) ----------------
__device__ __forceinline__ void gload_lds16(const void* g, void* lds) {
  __builtin_amdgcn_global_load_lds(
      (const __attribute__((address_space(1))) uint32_t*)g,
      (__attribute__((address_space(3))) uint32_t*)lds, 16, 0, 0);
}

__global__ __launch_bounds__(256) void gemm_u_kernel(const u16* __restrict__ A,
                                                     const u16* __restrict__ Bt,
                                                     const float* __restrict__ bfp,
                                                     const float* __restrict__ brp,
                                                     u16* __restrict__ xtilP,
                                                     u16* __restrict__ fP,
                                                     u16* __restrict__ rP) {
  __shared__ __align__(16) u16 As[128 * 32];
  __shared__ __align__(16) u16 Bs[128 * 32];
  const int bid  = blockIdx.x;
  const int bn   = bid % (NCOL_ / 128);
  const int bm   = bid / (NCOL_ / 128);
  const int m0   = bm * 128, n0 = bn * 128;
  const int tid  = threadIdx.x;
  const int w    = tid >> 6, lane = tid & 63;
  const int wr   = w >> 1, wc = w & 1;
  const int r    = lane & 15, half = lane >> 4;

  f32x4 acc[4][4] = {};

  const int jBase  = w * 2;
  const int rowSub = lane >> 2;        // 0..15 within chunk
  const int colOff = (lane & 3) * 8;   // u16 elems within 32-elem row

  for (int kt = 0; kt < K_; kt += 32) {
    __syncthreads();
    #pragma unroll
    for (int c0 = 0; c0 < 2; ++c0) {
      int j = jBase + c0;              // chunk 0..7, 1024 B each
      gload_lds16(A  + (uint64_t)(m0 + j * 16 + rowSub) * K_ + kt + colOff,
                  (char*)As + j * 1024);
      gload_lds16(Bt + (uint64_t)(n0 + j * 16 + rowSub) * K_ + kt + colOff,
                  (char*)Bs + j * 1024);
    }
    __syncthreads();

    bf16x8 af[4], bfr[4];
    #pragma unroll
    for (int mi = 0; mi < 4; ++mi) {
      int row = wr * 64 + mi * 16 + r;
      af[mi] = __builtin_bit_cast(bf16x8, *(const f32x4*)(&As[row * 32 + half * 8]));
    }
    #pragma unroll
    for (int ni = 0; ni < 4; ++ni) {
      int row = wc * 64 + ni * 16 + r;
      bfr[ni] = __builtin_bit_cast(bf16x8, *(const f32x4*)(&Bs[row * 32 + half * 8]));
    }
    #pragma unroll
    for (int mi = 0; mi < 4; ++mi)
      #pragma unroll
      for (int ni = 0; ni < 4; ++ni)
        acc[mi][ni] = __builtin_amdgcn_mfma_f32_16x16x32_bf16(af[mi], bfr[ni], acc[mi][ni], 0, 0, 0);
  }

  // epilogue: C/D layout col = lane&15, row = (lane>>4)*4 + i   [m89-verified]
  // N axis is planar: plane kk = n0/1024 is block-uniform; ch = n0%1024 + incol.
  const int kkPlane = n0 >> 10;             // 0: xtil, 1: f, 2: r
  const int chBase  = n0 & 1023;
  u16* plane = (kkPlane == 0) ? xtilP : (kkPlane == 1 ? fP : rP);
  const float* biasp = (kkPlane == 1) ? bfp : brp;
  #pragma unroll
  for (int mi = 0; mi < 4; ++mi) {
    #pragma unroll
    for (int ni = 0; ni < 4; ++ni) {
      int ch  = chBase + wc * 64 + ni * 16 + r;
      float bias = kkPlane ? biasp[ch] : 0.f;
      #pragma unroll
      for (int i = 0; i < 4; ++i) {
        int row = m0 + wr * 64 + mi * 16 + half * 4 + i;
        float v = acc[mi][ni][i];
        if (kkPlane) v = 1.f / (1.f + __expf(-(v + bias)));   // sigmoid for f,r (uniform branch)
        plane[(uint64_t)row * 1024 + ch] = f2h(v);
      }
    }
  }
}

// ---------------- chunked scan, phase A: per-chunk partial (c0=0) + decay product ----------------
__global__ __launch_bounds__(256) void scan_partial_kernel(const u16* __restrict__ xtilP,
                                                           const u16* __restrict__ fP,
                                                           float* __restrict__ cpart,
                                                           float* __restrict__ Pp) {
  int tid = blockIdx.x * 256 + threadIdx.x;       // 262144 = B * NCHUNK * 1024
  int ch = tid & 1023, chunk = (tid >> 10) & (NCHUNK - 1), b = tid >> 14;
  int d = ch >> 9;
  int l = chunk * CHUNK + (d ? CHUNK - 1 : 0);
  int64_t stride = d ? -1024 : 1024;
  uint64_t base = ((uint64_t)b * L_ + l) * 1024 + ch;
  float c = 0.f, P = 1.f;
  #pragma unroll 4
  for (int it = 0; it < CHUNK; ++it) {
    float f  = h2f(fP[base]);
    float xt = h2f(xtilP[base]);
    c = f * c + (1.f - f) * xt;
    P *= f;
    base += stride;
  }
  int o = (b * NCHUNK + chunk) * 1024 + ch;
  cpart[o] = c;
  Pp[o] = P;
}

// ---------------- phase B: sequential combine across chunks (per channel) ----------------
__global__ void scan_combine_kernel(const float* __restrict__ cpart, const float* __restrict__ Pp,
                                    float* __restrict__ cin, float* __restrict__ outc) {
  int tid = blockIdx.x * blockDim.x + threadIdx.x;  // 16384
  int ch = tid & 1023, b = tid >> 10, d = ch >> 9;
  float c = 0.f;
  for (int i = 0; i < NCHUNK; ++i) {
    int chunk = d ? (NCHUNK - 1 - i) : i;
    int o = (b * NCHUNK + chunk) * 1024 + ch;
    cin[o] = c;
    c = cpart[o] + Pp[o] * c;
  }
  outc[ch * B_ + b] = c;   // c.T layout (2H, B)
}

// ---------------- phase C: re-scan each chunk from true c_in, emit h ----------------
__global__ __launch_bounds__(256) void scan_final_kernel(const u16* __restrict__ xb,
                                                         const u16* __restrict__ xtilP,
                                                         const u16* __restrict__ fP,
                                                         const u16* __restrict__ rP,
                                                         const float* __restrict__ cin,
                                                         float* __restrict__ outh) {
  int tid = blockIdx.x * 256 + threadIdx.x;       // 262144
  int ch = tid & 1023, chunk = (tid >> 10) & (NCHUNK - 1), b = tid >> 14;
  int d = ch >> 9;
  int l = chunk * CHUNK + (d ? CHUNK - 1 : 0);
  int64_t stride = d ? -1024 : 1024;
  uint64_t base = ((uint64_t)b * L_ + l) * 1024 + ch;
  float c = cin[(b * NCHUNK + chunk) * 1024 + ch];
  #pragma unroll 2
  for (int it = 0; it < CHUNK; ++it) {
    float f    = h2f(fP[base]);
    float xt   = h2f(xtilP[base]);
    float rr   = h2f(rP[base]);
    float xres = bf2f(xb[base]);
    c = f * c + (1.f - f) * xt;
    float th = 1.f - 2.f / (__expf(2.f * c) + 1.f);   // tanh
    outh[base] = rr * th + (1.f - rr) * xres;
    base += stride;
  }
}

// ---------------- launch ----------------
extern "C" void kernel_launch(void* const* d_in, const int* in_sizes, int n_in,
                              void* d_out, int out_size, void* d_ws, size_t ws_size,
                              hipStream_t stream) {
  const float* x   = (const float*)d_in[0];
  const float* W   = (const float*)d_in[1];
  const float* bfp = (const float*)d_in[2];
  const float* brp = (const float*)d_in[3];

  float* outh = (float*)d_out;
  float* outc = outh + (size_t)B_ * L_ * DIN_;   // after (B, L, 2H)

  // ws layout (262 MiB total):
  u16* xb = (u16*)d_ws;                          // M_*K_ bf16      = 64 MiB (stays live: phase-C residual)
  u16* Wt = xb + (size_t)M_ * K_;                // NCOL_*K_ bf16   = 6 MiB (dead after GEMM)
  u16* xtilP = Wt + (size_t)NCOL_ * K_;          // M_*1024 fp16    = 64 MiB
  u16* fP    = xtilP + (size_t)M_ * 1024;        // 64 MiB
  u16* rP    = fP    + (size_t)M_ * 1024;        // 64 MiB
  // chunk-scan scratch aliases the dead Wt region (3 MiB <= 6 MiB):
  float* cpart = (float*)Wt;                     // B*NCHUNK*1024 f32 = 1 MiB
  float* Pp    = cpart + (size_t)B_ * NCHUNK * 1024;
  float* cin   = Pp    + (size_t)B_ * NCHUNK * 1024;

  cvt_x_kernel<<<(M_ * K_ / 4) / 256, 256, 0, stream>>>((const float4*)x, (ushort4*)xb);
  transpose_w_kernel<<<dim3(NCOL_ / 32, K_ / 32), dim3(32, 8), 0, stream>>>(W, Wt);
  gemm_u_kernel<<<(M_ / 128) * (NCOL_ / 128), 256, 0, stream>>>(xb, Wt, bfp, brp, xtilP, fP, rP);
  scan_partial_kernel<<<(B_ * NCHUNK * 1024) / 256, 256, 0, stream>>>(xtilP, fP, cpart, Pp);
  scan_combine_kernel<<<(B_ * 2 * H_) / 256, 256, 0, stream>>>(cpart, Pp, cin, outc);
  scan_final_kernel<<<(B_ * NCHUNK * 1024) / 256, 256, 0, stream>>>(xb, xtilP, fP, rP, cin, outh);
}

// Round 4
// 386.254 us; speedup vs baseline: 2.3625x; 1.2840x over previous
//
#include <hip/hip_runtime.h>
#include <stdint.h>

#define B_    16
#define L_    2048
#define DIN_  1024
#define H_    512
#define NCOL_ 3072          // 2 * H * 3
#define M_    (B_ * L_)     // 32768
#define K_    DIN_          // 1024
#define NCHUNK 16
#define CHUNK  128          // L_ / NCHUNK

typedef unsigned short u16;
typedef __bf16 bf16_t;
typedef bf16_t bf16x8 __attribute__((ext_vector_type(8)));
typedef float  f32x4  __attribute__((ext_vector_type(4)));

__device__ __forceinline__ u16 f2bf(float f) {
  union { float f; uint32_t u; } v; v.f = f;
  return (u16)((v.u + 0x7fffu + ((v.u >> 16) & 1u)) >> 16);  // RNE
}
__device__ __forceinline__ float bf2f(u16 b) {
  union { uint32_t u; float f; } v; v.u = ((uint32_t)b) << 16; return v.f;
}
__device__ __forceinline__ u16 f2h(float f) {
  _Float16 h = (_Float16)f; return *(u16*)&h;
}
__device__ __forceinline__ float h2f(u16 b) {
  _Float16 h = *(_Float16*)&b; return (float)h;
}

// ---------------- x f32 -> bf16 ----------------
__global__ void cvt_x_kernel(const float4* __restrict__ x, ushort4* __restrict__ xb) {
  int i = blockIdx.x * blockDim.x + threadIdx.x;   // exact grid, no bounds
  float4 v = x[i];
  ushort4 o;
  o.x = f2bf(v.x); o.y = f2bf(v.y); o.z = f2bf(v.z); o.w = f2bf(v.w);
  xb[i] = o;
}

// ---------------- W (K x N) -> Wt (N' x K) bf16, rows plane-permuted ----------------
// n' = k*1024 + d*512 + h  (so the GEMM N axis is planar: [xtil | f | r])
__global__ void transpose_w_kernel(const float* __restrict__ W, u16* __restrict__ Wt) {
  __shared__ float s[32][33];
  int n0 = blockIdx.x * 32;   // N tile
  int i0 = blockIdx.y * 32;   // K tile
  int tx = threadIdx.x, ty = threadIdx.y;  // (32, 8)
  #pragma unroll
  for (int y = 0; y < 32; y += 8)
    s[ty + y][tx] = W[(uint64_t)(i0 + ty + y) * NCOL_ + n0 + tx];
  __syncthreads();
  #pragma unroll
  for (int y = 0; y < 32; y += 8) {
    int n = n0 + ty + y;
    int kk = n % 3, d = n / 1536, h = (n % 1536) / 3;
    int np = kk * 1024 + d * 512 + h;
    Wt[(uint64_t)np * K_ + i0 + tx] = f2bf(s[tx][ty + y]);
  }
}

// ---------------- 256x256 8-phase GEMM (T2+T3+T4+T5), planar epilogue ----------------
__device__ __forceinline__ void gload_lds16(const void* g, void* lds) {
  __builtin_amdgcn_global_load_lds(
      (const __attribute__((address_space(1))) uint32_t*)g,
      (__attribute__((address_space(3))) uint32_t*)lds, 16, 0, 0);
}

__device__ __forceinline__ bf16x8 lds_rd(const u16* lds, int byteOff) {
  return __builtin_bit_cast(bf16x8, *(const f32x4*)((const char*)lds + byteOff));
}

// LDS map (bytes), per buffer (2 buffers of 64 KiB):
//   A-half0 [0,16K)  A-half1 [16K,32K)  B-half0 [32K,48K)  B-half1 [48K,64K)
// Each half: 128 rows x 64 bf16 (128 B/row), T2-swizzled:
//   physical granule of logical col-granule g in row r is g ^ (r&7)
//   (write side: linear gload_lds dest + pre-swizzled GLOBAL source;
//    read side: byte ^= (row&7)<<4  -> bank-conflict-free ds_read_b128)
__global__ __launch_bounds__(512, 2) void gemm_u_kernel(const u16* __restrict__ A,
                                                        const u16* __restrict__ Bt,
                                                        const float* __restrict__ bfp,
                                                        const float* __restrict__ brp,
                                                        u16* __restrict__ xtilP,
                                                        u16* __restrict__ fP,
                                                        u16* __restrict__ rP) {
  __shared__ __align__(16) u16 lds[65536];       // 128 KiB

  // XCD-aware bijective swizzle (nwg=1536, 1536%8==0), bn-fast for A-panel L2 reuse
  const int bid = blockIdx.x;
  const int swb = (bid & 7) * 192 + (bid >> 3);
  const int bm = swb / 12, bn = swb % 12;
  const int m0 = bm * 256, n0 = bn * 256;

  const int tid  = threadIdx.x;
  const int w    = tid >> 6, lane = tid & 63;
  const int wr   = w >> 2, wc = w & 3;          // 2M x 4N waves; per-wave out 128x64
  const int rr   = lane & 15, hs = lane >> 4;
  const int swzRd = (rr & 7) << 4;
  const int hsOff = hs * 16;

  // staging constants: round j, wave w writes LDS [region + j*8192 + w*1024 + lane*16]
  //  -> row = j*64 + w*8 + (lane>>3), granule = lane&7; source granule = (lane&7)^(row&7)
  const int rStage = w * 8 + (lane >> 3);
  const int sCol   = ((lane & 7) ^ ((lane >> 3) & 7)) * 8;
  const int ldsChunk = w * 1024;                 // wave-uniform lane base

  f32x4 acc[8][4] = {};

  auto stageA = [&](int bufBase, int kt) {
    #pragma unroll
    for (int h = 0; h < 2; ++h)
      #pragma unroll
      for (int j = 0; j < 2; ++j)
        gload_lds16(A + (uint64_t)(m0 + h * 128 + j * 64 + rStage) * K_ + kt + sCol,
                    (char*)lds + bufBase + h * 16384 + j * 8192 + ldsChunk);
  };
  auto stageB = [&](int bufBase, int kt) {
    #pragma unroll
    for (int h = 0; h < 2; ++h)
      #pragma unroll
      for (int j = 0; j < 2; ++j)
        gload_lds16(Bt + (uint64_t)(n0 + h * 128 + j * 64 + rStage) * K_ + kt + sCol,
                    (char*)lds + bufBase + 32768 + h * 16384 + j * 8192 + ldsChunk);
  };

  // prologue: tile 0 -> buf0, full drain once
  stageA(0, 0); stageB(0, 0);
  asm volatile("s_waitcnt vmcnt(0)" ::: "memory");
  __builtin_amdgcn_s_barrier();

  const int aHalfBase = wr * 16384;
  const int bHalfBase = 32768 + (wc >> 1) * 16384;
  const int rowB0 = (wc & 1) * 64;

  for (int t = 0; t < 16; ++t) {
    const int curBase = (t & 1) * 65536;
    const int nxtBase = curBase ^ 65536;
    const bool pf = (t < 15);
    const int ktNext = (t + 1) * 64;

    bf16x8 bF[4][2];
    // 4 phases per K-tile; quadrant q = acc rows {2q, 2q+1}
    #pragma unroll
    for (int q = 0; q < 4; ++q) {
      bf16x8 aF[2][2];
      #pragma unroll
      for (int m2 = 0; m2 < 2; ++m2) {
        const int rowA = (q * 2 + m2) * 16 + rr;
        #pragma unroll
        for (int ks = 0; ks < 2; ++ks)
          aF[m2][ks] = lds_rd(lds, curBase + aHalfBase + rowA * 128 + ((ks * 64 + hsOff) ^ swzRd));
      }
      if (q == 0) {
        #pragma unroll
        for (int ni = 0; ni < 4; ++ni) {
          const int rowB = rowB0 + ni * 16 + rr;
          #pragma unroll
          for (int ks = 0; ks < 2; ++ks)
            bF[ni][ks] = lds_rd(lds, curBase + bHalfBase + rowB * 128 + ((ks * 64 + hsOff) ^ swzRd));
        }
        if (pf) stageA(nxtBase, ktNext);   // prefetch into the other buffer
      }
      if (q == 1 && pf) stageB(nxtBase, ktNext);

      __builtin_amdgcn_sched_barrier(0);
      __builtin_amdgcn_s_barrier();                       // raw: no vmcnt drain
      asm volatile("s_waitcnt lgkmcnt(0)" ::: "memory");  // my ds_reads done
      __builtin_amdgcn_sched_barrier(0);                  // rule #18
      __builtin_amdgcn_s_setprio(1);
      #pragma unroll
      for (int m2 = 0; m2 < 2; ++m2)
        #pragma unroll
        for (int ni = 0; ni < 4; ++ni)
          #pragma unroll
          for (int ks = 0; ks < 2; ++ks)
            acc[q * 2 + m2][ni] = __builtin_amdgcn_mfma_f32_16x16x32_bf16(
                aF[m2][ks], bF[ni][ks], acc[q * 2 + m2][ni], 0, 0, 0);
      __builtin_amdgcn_s_setprio(0);
      if (q == 3 && pf) {
        // tile boundary: all 8 prefetch loads (issued at q0/q1, 2-3 phases of cover)
        // must be LDS-resident before anyone reads the new buffer after this barrier
        asm volatile("s_waitcnt vmcnt(0)" ::: "memory");
        __builtin_amdgcn_sched_barrier(0);
      }
      __builtin_amdgcn_s_barrier();
    }
  }

  // epilogue: C/D col = lane&15, row = (lane>>4)*4 + i  [m89-verified].
  // N planar: plane kk = n0>>10 block-uniform (256 | 1024); ch = (n0&1023) + incol.
  const int kkPlane = n0 >> 10;             // 0: xtil, 1: f, 2: r
  const int chBase  = n0 & 1023;
  u16* plane = (kkPlane == 0) ? xtilP : (kkPlane == 1 ? fP : rP);
  const float* biasp = (kkPlane == 1) ? bfp : brp;
  #pragma unroll
  for (int mi = 0; mi < 8; ++mi) {
    #pragma unroll
    for (int ni = 0; ni < 4; ++ni) {
      const int ch = chBase + wc * 64 + ni * 16 + rr;
      const float bias = kkPlane ? biasp[ch] : 0.f;
      #pragma unroll
      for (int i = 0; i < 4; ++i) {
        const int row = m0 + wr * 128 + mi * 16 + hs * 4 + i;
        float v = acc[mi][ni][i];
        if (kkPlane) v = 1.f / (1.f + __expf(-(v + bias)));   // uniform branch
        plane[(uint64_t)row * 1024 + ch] = f2h(v);
      }
    }
  }
}

// ---------------- chunked scan, phase A: per-chunk partial (c0=0) + decay product ----------------
__global__ __launch_bounds__(256) void scan_partial_kernel(const u16* __restrict__ xtilP,
                                                           const u16* __restrict__ fP,
                                                           float* __restrict__ cpart,
                                                           float* __restrict__ Pp) {
  int tid = blockIdx.x * 256 + threadIdx.x;       // 262144 = B * NCHUNK * 1024
  int ch = tid & 1023, chunk = (tid >> 10) & (NCHUNK - 1), b = tid >> 14;
  int d = ch >> 9;
  int l = chunk * CHUNK + (d ? CHUNK - 1 : 0);
  int64_t stride = d ? -1024 : 1024;
  uint64_t base = ((uint64_t)b * L_ + l) * 1024 + ch;
  float c = 0.f, P = 1.f;
  #pragma unroll 4
  for (int it = 0; it < CHUNK; ++it) {
    float f  = h2f(fP[base]);
    float xt = h2f(xtilP[base]);
    c = f * c + (1.f - f) * xt;
    P *= f;
    base += stride;
  }
  int o = (b * NCHUNK + chunk) * 1024 + ch;
  cpart[o] = c;
  Pp[o] = P;
}

// ---------------- phase B: sequential combine across chunks (per channel) ----------------
__global__ void scan_combine_kernel(const float* __restrict__ cpart, const float* __restrict__ Pp,
                                    float* __restrict__ cin, float* __restrict__ outc) {
  int tid = blockIdx.x * blockDim.x + threadIdx.x;  // 16384
  int ch = tid & 1023, b = tid >> 10, d = ch >> 9;
  float c = 0.f;
  for (int i = 0; i < NCHUNK; ++i) {
    int chunk = d ? (NCHUNK - 1 - i) : i;
    int o = (b * NCHUNK + chunk) * 1024 + ch;
    cin[o] = c;
    c = cpart[o] + Pp[o] * c;
  }
  outc[ch * B_ + b] = c;   // c.T layout (2H, B)
}

// ---------------- phase C: re-scan each chunk from true c_in, emit h ----------------
__global__ __launch_bounds__(256) void scan_final_kernel(const u16* __restrict__ xb,
                                                         const u16* __restrict__ xtilP,
                                                         const u16* __restrict__ fP,
                                                         const u16* __restrict__ rP,
                                                         const float* __restrict__ cin,
                                                         float* __restrict__ outh) {
  int tid = blockIdx.x * 256 + threadIdx.x;       // 262144
  int ch = tid & 1023, chunk = (tid >> 10) & (NCHUNK - 1), b = tid >> 14;
  int d = ch >> 9;
  int l = chunk * CHUNK + (d ? CHUNK - 1 : 0);
  int64_t stride = d ? -1024 : 1024;
  uint64_t base = ((uint64_t)b * L_ + l) * 1024 + ch;
  float c = cin[(b * NCHUNK + chunk) * 1024 + ch];
  #pragma unroll 2
  for (int it = 0; it < CHUNK; ++it) {
    float f    = h2f(fP[base]);
    float xt   = h2f(xtilP[base]);
    float rr   = h2f(rP[base]);
    float xres = bf2f(xb[base]);
    c = f * c + (1.f - f) * xt;
    float th = 1.f - 2.f / (__expf(2.f * c) + 1.f);   // tanh
    outh[base] = rr * th + (1.f - rr) * xres;
    base += stride;
  }
}

// ---------------- launch ----------------
extern "C" void kernel_launch(void* const* d_in, const int* in_sizes, int n_in,
                              void* d_out, int out_size, void* d_ws, size_t ws_size,
                              hipStream_t stream) {
  const float* x   = (const float*)d_in[0];
  const float* W   = (const float*)d_in[1];
  const float* bfp = (const float*)d_in[2];
  const float* brp = (const float*)d_in[3];

  float* outh = (float*)d_out;
  float* outc = outh + (size_t)B_ * L_ * DIN_;   // after (B, L, 2H)

  // ws layout (262 MiB total):
  u16* xb = (u16*)d_ws;                          // M_*K_ bf16      = 64 MiB (live: phase-C residual)
  u16* Wt = xb + (size_t)M_ * K_;                // NCOL_*K_ bf16   = 6 MiB (dead after GEMM)
  u16* xtilP = Wt + (size_t)NCOL_ * K_;          // M_*1024 fp16    = 64 MiB
  u16* fP    = xtilP + (size_t)M_ * 1024;        // 64 MiB
  u16* rP    = fP    + (size_t)M_ * 1024;        // 64 MiB
  // chunk-scan scratch aliases the dead Wt region (3 MiB <= 6 MiB):
  float* cpart = (float*)Wt;                     // B*NCHUNK*1024 f32 = 1 MiB
  float* Pp    = cpart + (size_t)B_ * NCHUNK * 1024;
  float* cin   = Pp    + (size_t)B_ * NCHUNK * 1024;

  cvt_x_kernel<<<(M_ * K_ / 4) / 256, 256, 0, stream>>>((const float4*)x, (ushort4*)xb);
  transpose_w_kernel<<<dim3(NCOL_ / 32, K_ / 32), dim3(32, 8), 0, stream>>>(W, Wt);
  gemm_u_kernel<<<(M_ / 256) * (NCOL_ / 256), 512, 0, stream>>>(xb, Wt, bfp, brp, xtilP, fP, rP);
  scan_partial_kernel<<<(B_ * NCHUNK * 1024) / 256, 256, 0, stream>>>(xtilP, fP, cpart, Pp);
  scan_combine_kernel<<<(B_ * 2 * H_) / 256, 256, 0, stream>>>(cpart, Pp, cin, outc);
  scan_final_kernel<<<(B_ * NCHUNK * 1024) / 256, 256, 0, stream>>>(xb, xtilP, fP, rP, cin, outh);
}

// Round 5
// 386.237 us; speedup vs baseline: 2.3626x; 1.0000x over previous
//
#include <hip/hip_runtime.h>
#include <stdint.h>

#define B_    16
#define L_    2048
#define DIN_  1024
#define H_    512
#define NCOL_ 3072          // 2 * H * 3
#define M_    (B_ * L_)     // 32768
#define K_    DIN_          // 1024
#define NCHUNK 16
#define CHUNK  128          // L_ / NCHUNK

typedef unsigned short u16;
typedef __bf16 bf16_t;
typedef bf16_t bf16x8 __attribute__((ext_vector_type(8)));
typedef float  f32x4  __attribute__((ext_vector_type(4)));

__device__ __forceinline__ u16 f2bf(float f) {
  union { float f; uint32_t u; } v; v.f = f;
  return (u16)((v.u + 0x7fffu + ((v.u >> 16) & 1u)) >> 16);  // RNE
}
__device__ __forceinline__ float bf2f(u16 b) {
  union { uint32_t u; float f; } v; v.u = ((uint32_t)b) << 16; return v.f;
}
__device__ __forceinline__ u16 f2h(float f) {
  _Float16 h = (_Float16)f; return *(u16*)&h;
}
__device__ __forceinline__ float h2f(u16 b) {
  _Float16 h = *(_Float16*)&b; return (float)h;
}

// ---------------- x f32 -> bf16 ----------------
__global__ void cvt_x_kernel(const float4* __restrict__ x, ushort4* __restrict__ xb) {
  int i = blockIdx.x * blockDim.x + threadIdx.x;   // exact grid, no bounds
  float4 v = x[i];
  ushort4 o;
  o.x = f2bf(v.x); o.y = f2bf(v.y); o.z = f2bf(v.z); o.w = f2bf(v.w);
  xb[i] = o;
}

// ---------------- W (K x N) -> Wt (N' x K) bf16, rows plane-permuted ----------------
// n' = k*1024 + d*512 + h  (so the GEMM N axis is planar: [xtil | f | r])
__global__ void transpose_w_kernel(const float* __restrict__ W, u16* __restrict__ Wt) {
  __shared__ float s[32][33];
  int n0 = blockIdx.x * 32;   // N tile
  int i0 = blockIdx.y * 32;   // K tile
  int tx = threadIdx.x, ty = threadIdx.y;  // (32, 8)
  #pragma unroll
  for (int y = 0; y < 32; y += 8)
    s[ty + y][tx] = W[(uint64_t)(i0 + ty + y) * NCOL_ + n0 + tx];
  __syncthreads();
  #pragma unroll
  for (int y = 0; y < 32; y += 8) {
    int n = n0 + ty + y;
    int kk = n % 3, d = n / 1536, h = (n % 1536) / 3;
    int np = kk * 1024 + d * 512 + h;
    Wt[(uint64_t)np * K_ + i0 + tx] = f2bf(s[tx][ty + y]);
  }
}

// ---------------- 256x256 8-phase GEMM (T2+T3+T4+T5), planar epilogue ----------------
__device__ __forceinline__ void gload_lds16(const void* g, void* lds) {
  __builtin_amdgcn_global_load_lds(
      (const __attribute__((address_space(1))) uint32_t*)g,
      (__attribute__((address_space(3))) uint32_t*)lds, 16, 0, 0);
}

__device__ __forceinline__ bf16x8 lds_rd(const u16* lds, int byteOff) {
  return __builtin_bit_cast(bf16x8, *(const f32x4*)((const char*)lds + byteOff));
}

// LDS map (bytes), per buffer (2 buffers of 64 KiB):
//   A-half0 [0,16K)  A-half1 [16K,32K)  B-half0 [32K,48K)  B-half1 [48K,64K)
// Each half: 128 rows x 64 bf16 (128 B/row), T2-swizzled:
//   physical granule of logical col-granule g in row r is g ^ (r&7)
//   (write side: linear gload_lds dest + pre-swizzled GLOBAL source;
//    read side: byte ^= (row&7)<<4  -> bank-conflict-free ds_read_b128)
__global__ __launch_bounds__(512, 2) void gemm_u_kernel(const u16* __restrict__ A,
                                                        const u16* __restrict__ Bt,
                                                        const float* __restrict__ bfp,
                                                        const float* __restrict__ brp,
                                                        u16* __restrict__ xtilP,
                                                        u16* __restrict__ fP,
                                                        u16* __restrict__ rP) {
  __shared__ __align__(16) u16 lds[65536];       // 128 KiB

  // Block->tile mapping, L2-traffic-minimizing [R5 fix]:
  //  - XCD-chunked M: XCD x owns bm in [16x, 16x+16) -> each A panel (512 KB)
  //    is fetched by exactly one XCD's L2 (A total = 64 MB, once).
  //  - bm-fast within the XCD: the 32 concurrent blocks of a round span
  //    16 bm x 2 bn -> per-round B slice = 2 cols x 512 KB = 1 MB (L2-resident),
  //    and each A K-tile is read by its 2 co-launched bn-partners ~simultaneously
  //    (2nd read is an L2 hit). Prev bn-fast order: 6 MB B set > 4 MiB L2 ->
  //    B re-fetched every round (288 MB observed).
  const int bid = blockIdx.x;
  const int xcd = bid & 7;
  const int li  = bid >> 3;                     // 0..191 within XCD
  const int bm  = xcd * 16 + (li & 15);
  const int bn  = li >> 4;                      // 0..11, 2 per 32-block round
  const int m0 = bm * 256, n0 = bn * 256;

  const int tid  = threadIdx.x;
  const int w    = tid >> 6, lane = tid & 63;
  const int wr   = w >> 2, wc = w & 3;          // 2M x 4N waves; per-wave out 128x64
  const int rr   = lane & 15, hs = lane >> 4;
  const int swzRd = (rr & 7) << 4;
  const int hsOff = hs * 16;

  // staging constants: round j, wave w writes LDS [region + j*8192 + w*1024 + lane*16]
  //  -> row = j*64 + w*8 + (lane>>3), granule = lane&7; source granule = (lane&7)^(row&7)
  const int rStage = w * 8 + (lane >> 3);
  const int sCol   = ((lane & 7) ^ ((lane >> 3) & 7)) * 8;
  const int ldsChunk = w * 1024;                 // wave-uniform lane base

  f32x4 acc[8][4] = {};

  auto stageA = [&](int bufBase, int kt) {
    #pragma unroll
    for (int h = 0; h < 2; ++h)
      #pragma unroll
      for (int j = 0; j < 2; ++j)
        gload_lds16(A + (uint64_t)(m0 + h * 128 + j * 64 + rStage) * K_ + kt + sCol,
                    (char*)lds + bufBase + h * 16384 + j * 8192 + ldsChunk);
  };
  auto stageB = [&](int bufBase, int kt) {
    #pragma unroll
    for (int h = 0; h < 2; ++h)
      #pragma unroll
      for (int j = 0; j < 2; ++j)
        gload_lds16(Bt + (uint64_t)(n0 + h * 128 + j * 64 + rStage) * K_ + kt + sCol,
                    (char*)lds + bufBase + 32768 + h * 16384 + j * 8192 + ldsChunk);
  };

  // prologue: tile 0 -> buf0, full drain once
  stageA(0, 0); stageB(0, 0);
  asm volatile("s_waitcnt vmcnt(0)" ::: "memory");
  __builtin_amdgcn_s_barrier();

  const int aHalfBase = wr * 16384;
  const int bHalfBase = 32768 + (wc >> 1) * 16384;
  const int rowB0 = (wc & 1) * 64;

  for (int t = 0; t < 16; ++t) {
    const int curBase = (t & 1) * 65536;
    const int nxtBase = curBase ^ 65536;
    const bool pf = (t < 15);
    const int ktNext = (t + 1) * 64;

    bf16x8 bF[4][2];
    // 4 phases per K-tile; quadrant q = acc rows {2q, 2q+1}
    #pragma unroll
    for (int q = 0; q < 4; ++q) {
      bf16x8 aF[2][2];
      #pragma unroll
      for (int m2 = 0; m2 < 2; ++m2) {
        const int rowA = (q * 2 + m2) * 16 + rr;
        #pragma unroll
        for (int ks = 0; ks < 2; ++ks)
          aF[m2][ks] = lds_rd(lds, curBase + aHalfBase + rowA * 128 + ((ks * 64 + hsOff) ^ swzRd));
      }
      if (q == 0) {
        #pragma unroll
        for (int ni = 0; ni < 4; ++ni) {
          const int rowB = rowB0 + ni * 16 + rr;
          #pragma unroll
          for (int ks = 0; ks < 2; ++ks)
            bF[ni][ks] = lds_rd(lds, curBase + bHalfBase + rowB * 128 + ((ks * 64 + hsOff) ^ swzRd));
        }
        if (pf) stageA(nxtBase, ktNext);   // prefetch into the other buffer
      }
      if (q == 1 && pf) stageB(nxtBase, ktNext);

      __builtin_amdgcn_sched_barrier(0);
      __builtin_amdgcn_s_barrier();                       // raw: no vmcnt drain
      asm volatile("s_waitcnt lgkmcnt(0)" ::: "memory");  // my ds_reads done
      __builtin_amdgcn_sched_barrier(0);                  // rule #18
      __builtin_amdgcn_s_setprio(1);
      #pragma unroll
      for (int m2 = 0; m2 < 2; ++m2)
        #pragma unroll
        for (int ni = 0; ni < 4; ++ni)
          #pragma unroll
          for (int ks = 0; ks < 2; ++ks)
            acc[q * 2 + m2][ni] = __builtin_amdgcn_mfma_f32_16x16x32_bf16(
                aF[m2][ks], bF[ni][ks], acc[q * 2 + m2][ni], 0, 0, 0);
      __builtin_amdgcn_s_setprio(0);
      if (q == 3 && pf) {
        // tile boundary: all 8 prefetch loads (issued at q0/q1, 2-3 phases of cover)
        // must be LDS-resident before anyone reads the new buffer after this barrier
        asm volatile("s_waitcnt vmcnt(0)" ::: "memory");
        __builtin_amdgcn_sched_barrier(0);
      }
      __builtin_amdgcn_s_barrier();
    }
  }

  // epilogue: C/D col = lane&15, row = (lane>>4)*4 + i  [m89-verified].
  // N planar: plane kk = n0>>10 block-uniform (256 | 1024); ch = (n0&1023) + incol.
  const int kkPlane = n0 >> 10;             // 0: xtil, 1: f, 2: r
  const int chBase  = n0 & 1023;
  u16* plane = (kkPlane == 0) ? xtilP : (kkPlane == 1 ? fP : rP);
  const float* biasp = (kkPlane == 1) ? bfp : brp;
  #pragma unroll
  for (int mi = 0; mi < 8; ++mi) {
    #pragma unroll
    for (int ni = 0; ni < 4; ++ni) {
      const int ch = chBase + wc * 64 + ni * 16 + rr;
      const float bias = kkPlane ? biasp[ch] : 0.f;
      #pragma unroll
      for (int i = 0; i < 4; ++i) {
        const int row = m0 + wr * 128 + mi * 16 + hs * 4 + i;
        float v = acc[mi][ni][i];
        if (kkPlane) v = 1.f / (1.f + __expf(-(v + bias)));   // uniform branch
        plane[(uint64_t)row * 1024 + ch] = f2h(v);
      }
    }
  }
}

// ---------------- chunked scan, phase A: per-chunk partial (c0=0) + decay product ----------------
__global__ __launch_bounds__(256) void scan_partial_kernel(const u16* __restrict__ xtilP,
                                                           const u16* __restrict__ fP,
                                                           float* __restrict__ cpart,
                                                           float* __restrict__ Pp) {
  int tid = blockIdx.x * 256 + threadIdx.x;       // 262144 = B * NCHUNK * 1024
  int ch = tid & 1023, chunk = (tid >> 10) & (NCHUNK - 1), b = tid >> 14;
  int d = ch >> 9;
  int l = chunk * CHUNK + (d ? CHUNK - 1 : 0);
  int64_t stride = d ? -1024 : 1024;
  uint64_t base = ((uint64_t)b * L_ + l) * 1024 + ch;
  float c = 0.f, P = 1.f;
  #pragma unroll 4
  for (int it = 0; it < CHUNK; ++it) {
    float f  = h2f(fP[base]);
    float xt = h2f(xtilP[base]);
    c = f * c + (1.f - f) * xt;
    P *= f;
    base += stride;
  }
  int o = (b * NCHUNK + chunk) * 1024 + ch;
  cpart[o] = c;
  Pp[o] = P;
}

// ---------------- phase B: sequential combine across chunks (per channel) ----------------
__global__ void scan_combine_kernel(const float* __restrict__ cpart, const float* __restrict__ Pp,
                                    float* __restrict__ cin, float* __restrict__ outc) {
  int tid = blockIdx.x * blockDim.x + threadIdx.x;  // 16384
  int ch = tid & 1023, b = tid >> 10, d = ch >> 9;
  float c = 0.f;
  for (int i = 0; i < NCHUNK; ++i) {
    int chunk = d ? (NCHUNK - 1 - i) : i;
    int o = (b * NCHUNK + chunk) * 1024 + ch;
    cin[o] = c;
    c = cpart[o] + Pp[o] * c;
  }
  outc[ch * B_ + b] = c;   // c.T layout (2H, B)
}

// ---------------- phase C: re-scan each chunk from true c_in, emit h ----------------
__global__ __launch_bounds__(256) void scan_final_kernel(const u16* __restrict__ xb,
                                                         const u16* __restrict__ xtilP,
                                                         const u16* __restrict__ fP,
                                                         const u16* __restrict__ rP,
                                                         const float* __restrict__ cin,
                                                         float* __restrict__ outh) {
  int tid = blockIdx.x * 256 + threadIdx.x;       // 262144
  int ch = tid & 1023, chunk = (tid >> 10) & (NCHUNK - 1), b = tid >> 14;
  int d = ch >> 9;
  int l = chunk * CHUNK + (d ? CHUNK - 1 : 0);
  int64_t stride = d ? -1024 : 1024;
  uint64_t base = ((uint64_t)b * L_ + l) * 1024 + ch;
  float c = cin[(b * NCHUNK + chunk) * 1024 + ch];
  #pragma unroll 2
  for (int it = 0; it < CHUNK; ++it) {
    float f    = h2f(fP[base]);
    float xt   = h2f(xtilP[base]);
    float rr   = h2f(rP[base]);
    float xres = bf2f(xb[base]);
    c = f * c + (1.f - f) * xt;
    float th = 1.f - 2.f / (__expf(2.f * c) + 1.f);   // tanh
    outh[base] = rr * th + (1.f - rr) * xres;
    base += stride;
  }
}

// ---------------- launch ----------------
extern "C" void kernel_launch(void* const* d_in, const int* in_sizes, int n_in,
                              void* d_out, int out_size, void* d_ws, size_t ws_size,
                              hipStream_t stream) {
  const float* x   = (const float*)d_in[0];
  const float* W   = (const float*)d_in[1];
  const float* bfp = (const float*)d_in[2];
  const float* brp = (const float*)d_in[3];

  float* outh = (float*)d_out;
  float* outc = outh + (size_t)B_ * L_ * DIN_;   // after (B, L, 2H)

  // ws layout (262 MiB total):
  u16* xb = (u16*)d_ws;                          // M_*K_ bf16      = 64 MiB (live: phase-C residual)
  u16* Wt = xb + (size_t)M_ * K_;                // NCOL_*K_ bf16   = 6 MiB (dead after GEMM)
  u16* xtilP = Wt + (size_t)NCOL_ * K_;          // M_*1024 fp16    = 64 MiB
  u16* fP    = xtilP + (size_t)M_ * 1024;        // 64 MiB
  u16* rP    = fP    + (size_t)M_ * 1024;        // 64 MiB
  // chunk-scan scratch aliases the dead Wt region (3 MiB <= 6 MiB):
  float* cpart = (float*)Wt;                     // B*NCHUNK*1024 f32 = 1 MiB
  float* Pp    = cpart + (size_t)B_ * NCHUNK * 1024;
  float* cin   = Pp    + (size_t)B_ * NCHUNK * 1024;

  cvt_x_kernel<<<(M_ * K_ / 4) / 256, 256, 0, stream>>>((const float4*)x, (ushort4*)xb);
  transpose_w_kernel<<<dim3(NCOL_ / 32, K_ / 32), dim3(32, 8), 0, stream>>>(W, Wt);
  gemm_u_kernel<<<(M_ / 256) * (NCOL_ / 256), 512, 0, stream>>>(xb, Wt, bfp, brp, xtilP, fP, rP);
  scan_partial_kernel<<<(B_ * NCHUNK * 1024) / 256, 256, 0, stream>>>(xtilP, fP, cpart, Pp);
  scan_combine_kernel<<<(B_ * 2 * H_) / 256, 256, 0, stream>>>(cpart, Pp, cin, outc);
  scan_final_kernel<<<(B_ * NCHUNK * 1024) / 256, 256, 0, stream>>>(xb, xtilP, fP, rP, cin, outh);
}

// Round 6
// 384.595 us; speedup vs baseline: 2.3727x; 1.0043x over previous
//
#include <hip/hip_runtime.h>
#include <stdint.h>

#define B_    16
#define L_    2048
#define DIN_  1024
#define H_    512
#define NCOL_ 3072          // 2 * H * 3
#define M_    (B_ * L_)     // 32768
#define K_    DIN_          // 1024
#define NCHUNK 16
#define CHUNK  128          // L_ / NCHUNK

typedef unsigned short u16;
typedef __bf16 bf16_t;
typedef bf16_t bf16x8 __attribute__((ext_vector_type(8)));
typedef float  f32x4  __attribute__((ext_vector_type(4)));

__device__ __forceinline__ u16 f2bf(float f) {
  union { float f; uint32_t u; } v; v.f = f;
  return (u16)((v.u + 0x7fffu + ((v.u >> 16) & 1u)) >> 16);  // RNE
}
__device__ __forceinline__ float bf2f(u16 b) {
  union { uint32_t u; float f; } v; v.u = ((uint32_t)b) << 16; return v.f;
}
__device__ __forceinline__ u16 f2h(float f) {
  _Float16 h = (_Float16)f; return *(u16*)&h;
}
__device__ __forceinline__ float h2f(u16 b) {
  _Float16 h = *(_Float16*)&b; return (float)h;
}

// ---------------- x f32 -> bf16 ----------------
__global__ void cvt_x_kernel(const float4* __restrict__ x, ushort4* __restrict__ xb) {
  int i = blockIdx.x * blockDim.x + threadIdx.x;   // exact grid, no bounds
  float4 v = x[i];
  ushort4 o;
  o.x = f2bf(v.x); o.y = f2bf(v.y); o.z = f2bf(v.z); o.w = f2bf(v.w);
  xb[i] = o;
}

// ---------------- W (K x N) -> Wt (N' x K) bf16, rows plane-permuted ----------------
// n' = k*1024 + d*512 + h  (so the GEMM N axis is planar: [xtil | f | r])
__global__ void transpose_w_kernel(const float* __restrict__ W, u16* __restrict__ Wt) {
  __shared__ float s[32][33];
  int n0 = blockIdx.x * 32;   // N tile
  int i0 = blockIdx.y * 32;   // K tile
  int tx = threadIdx.x, ty = threadIdx.y;  // (32, 8)
  #pragma unroll
  for (int y = 0; y < 32; y += 8)
    s[ty + y][tx] = W[(uint64_t)(i0 + ty + y) * NCOL_ + n0 + tx];
  __syncthreads();
  #pragma unroll
  for (int y = 0; y < 32; y += 8) {
    int n = n0 + ty + y;
    int kk = n % 3, d = n / 1536, h = (n % 1536) / 3;
    int np = kk * 1024 + d * 512 + h;
    Wt[(uint64_t)np * K_ + i0 + tx] = f2bf(s[tx][ty + y]);
  }
}

// ---------------- 256x256 GEMM, 2-phase/tile, A dbuf + B 3buf, counted vmcnt ----------------
__device__ __forceinline__ void gload_lds16(const void* g, void* lds) {
  __builtin_amdgcn_global_load_lds(
      (const __attribute__((address_space(1))) uint32_t*)g,
      (__attribute__((address_space(3))) uint32_t*)lds, 16, 0, 0);
}

__device__ __forceinline__ bf16x8 lds_rd(const u16* lds, int byteOff) {
  return __builtin_bit_cast(bf16x8, *(const f32x4*)((const char*)lds + byteOff));
}

// LDS map (bytes), 160 KiB total:
//   A bufs (2): [0, 32768), [32768, 65536)           -- 256 rows x 64 bf16, 128 B/row
//   B bufs (3): 65536 + {0,1,2} * 32768              -- same shape
// T2 swizzle per 128-B row: phys granule g_p = g_l ^ (row&7)
//   write: linear gload_lds dest + pre-swizzled GLOBAL source granule
//   read:  byte ^= (row&7)<<4  -> conflict-free ds_read_b128
//
// Schedule per K-tile t (T3+T4+T5):
//   P0: issue stageA(t+1)->Abuf[(t+1)&1]; ds_read aF rows 0..63 + all bF;
//       barrier; lgkm0; 32 MFMA (acc rows 0..3); barrier
//   P1: issue stageB(t+2)->Bbuf[(t+2)%3]; ds_read aF rows 64..127;
//       barrier; lgkm0; 32 MFMA (acc rows 4..7);
//       vmcnt(4)  [A(t+1),B(t+1) done; B(t+2) stays IN FLIGHT]; barrier
// Tail: t=14 waits vmcnt(0); t=15 stages nothing.
__global__ __launch_bounds__(512, 2) void gemm_u_kernel(const u16* __restrict__ A,
                                                        const u16* __restrict__ Bt,
                                                        const float* __restrict__ bfp,
                                                        const float* __restrict__ brp,
                                                        u16* __restrict__ xtilP,
                                                        u16* __restrict__ fP,
                                                        u16* __restrict__ rP) {
  __shared__ __align__(16) u16 lds[81920];       // 160 KiB

  // Block->tile mapping (R5): XCD-chunked M (16 bm per XCD), bm-fast within XCD.
  const int bid = blockIdx.x;
  const int xcd = bid & 7;
  const int li  = bid >> 3;                     // 0..191 within XCD
  const int bm  = xcd * 16 + (li & 15);
  const int bn  = li >> 4;                      // 0..11
  const int m0 = bm * 256, n0 = bn * 256;

  const int tid  = threadIdx.x;
  const int w    = tid >> 6, lane = tid & 63;
  const int wr   = w >> 2, wc = w & 3;          // 2M x 4N waves; per-wave out 128x64
  const int rr   = lane & 15, hs = lane >> 4;
  const int swzRd = (rr & 7) << 4;
  const int hsOff = hs * 16;

  // staging: round (h,j), wave w writes LDS [buf + h*16384 + j*8192 + w*1024 + lane*16]
  //  -> row = h*128 + j*64 + w*8 + (lane>>3); granule = lane&7; src granule = (lane&7)^(row&7)
  const int rStage = w * 8 + (lane >> 3);
  const int sCol   = ((lane & 7) ^ ((lane >> 3) & 7)) * 8;
  const int ldsChunk = w * 1024;

  f32x4 acc[8][4] = {};

  auto stageA = [&](int bufBase, int kt) {
    #pragma unroll
    for (int h = 0; h < 2; ++h)
      #pragma unroll
      for (int j = 0; j < 2; ++j)
        gload_lds16(A + (uint64_t)(m0 + h * 128 + j * 64 + rStage) * K_ + kt + sCol,
                    (char*)lds + bufBase + h * 16384 + j * 8192 + ldsChunk);
  };
  auto stageB = [&](int bufBase, int kt) {
    #pragma unroll
    for (int h = 0; h < 2; ++h)
      #pragma unroll
      for (int j = 0; j < 2; ++j)
        gload_lds16(Bt + (uint64_t)(n0 + h * 128 + j * 64 + rStage) * K_ + kt + sCol,
                    (char*)lds + bufBase + h * 16384 + j * 8192 + ldsChunk);
  };

  // prologue: A(0)->Ab0, B(0)->Bb0, B(1)->Bb1; require A0,B0; leave B1 in flight
  stageA(0, 0);
  stageB(65536, 0);
  stageB(65536 + 32768, 64);
  asm volatile("s_waitcnt vmcnt(4)" ::: "memory");
  __builtin_amdgcn_sched_barrier(0);
  __builtin_amdgcn_s_barrier();

  const int aHalfBase = wr * 16384;             // within A buf
  const int bQuart    = (wc >> 1) * 16384;      // within B buf
  const int rowB0     = (wc & 1) * 64;

  int b3 = 0;                                    // t % 3
  for (int t = 0; t < 16; ++t) {
    const int curA = (t & 1) << 15;
    const int curB = 65536 + b3 * 32768;
    const int b3n2 = (b3 >= 1) ? (b3 - 1) : 2;   // (t+2) % 3

    // ---------------- P0 ----------------
    if (t < 15) stageA((~t & 1) << 15, (t + 1) * 64);
    bf16x8 aF[4][2], bF[4][2];
    #pragma unroll
    for (int a = 0; a < 4; ++a)
      #pragma unroll
      for (int ks = 0; ks < 2; ++ks)
        aF[a][ks] = lds_rd(lds, curA + aHalfBase + (a * 16 + rr) * 128 + ((ks * 64 + hsOff) ^ swzRd));
    #pragma unroll
    for (int ni = 0; ni < 4; ++ni)
      #pragma unroll
      for (int ks = 0; ks < 2; ++ks)
        bF[ni][ks] = lds_rd(lds, curB + bQuart + (rowB0 + ni * 16 + rr) * 128 + ((ks * 64 + hsOff) ^ swzRd));
    __builtin_amdgcn_sched_barrier(0);
    __builtin_amdgcn_s_barrier();
    asm volatile("s_waitcnt lgkmcnt(0)" ::: "memory");
    __builtin_amdgcn_sched_barrier(0);                  // rule #18
    __builtin_amdgcn_s_setprio(1);
    #pragma unroll
    for (int a = 0; a < 4; ++a)
      #pragma unroll
      for (int ni = 0; ni < 4; ++ni)
        #pragma unroll
        for (int ks = 0; ks < 2; ++ks)
          acc[a][ni] = __builtin_amdgcn_mfma_f32_16x16x32_bf16(aF[a][ks], bF[ni][ks], acc[a][ni], 0, 0, 0);
    __builtin_amdgcn_s_setprio(0);
    __builtin_amdgcn_sched_barrier(0);
    __builtin_amdgcn_s_barrier();

    // ---------------- P1 ----------------
    if (t < 14) stageB(65536 + b3n2 * 32768, (t + 2) * 64);
    bf16x8 aG[4][2];
    #pragma unroll
    for (int a = 0; a < 4; ++a)
      #pragma unroll
      for (int ks = 0; ks < 2; ++ks)
        aG[a][ks] = lds_rd(lds, curA + aHalfBase + ((a + 4) * 16 + rr) * 128 + ((ks * 64 + hsOff) ^ swzRd));
    __builtin_amdgcn_sched_barrier(0);
    __builtin_amdgcn_s_barrier();
    asm volatile("s_waitcnt lgkmcnt(0)" ::: "memory");
    __builtin_amdgcn_sched_barrier(0);
    __builtin_amdgcn_s_setprio(1);
    #pragma unroll
    for (int a = 0; a < 4; ++a)
      #pragma unroll
      for (int ni = 0; ni < 4; ++ni)
        #pragma unroll
        for (int ks = 0; ks < 2; ++ks)
          acc[a + 4][ni] = __builtin_amdgcn_mfma_f32_16x16x32_bf16(aG[a][ks], bF[ni][ks], acc[a + 4][ni], 0, 0, 0);
    __builtin_amdgcn_s_setprio(0);
    if (t < 14) {
      asm volatile("s_waitcnt vmcnt(4)" ::: "memory");   // A(t+1),B(t+1) done; B(t+2) flying
      __builtin_amdgcn_sched_barrier(0);
    } else if (t == 14) {
      asm volatile("s_waitcnt vmcnt(0)" ::: "memory");   // tail drain: A(15),B(15)
      __builtin_amdgcn_sched_barrier(0);
    }
    __builtin_amdgcn_s_barrier();

    b3 = (b3 + 1 == 3) ? 0 : b3 + 1;
  }

  // epilogue: C/D col = lane&15, row = (lane>>4)*4 + i  [m89-verified].
  // N planar: plane kk = n0>>10 block-uniform; ch = (n0&1023) + incol.
  const int kkPlane = n0 >> 10;             // 0: xtil, 1: f, 2: r
  const int chBase  = n0 & 1023;
  u16* plane = (kkPlane == 0) ? xtilP : (kkPlane == 1 ? fP : rP);
  const float* biasp = (kkPlane == 1) ? bfp : brp;
  #pragma unroll
  for (int mi = 0; mi < 8; ++mi) {
    #pragma unroll
    for (int ni = 0; ni < 4; ++ni) {
      const int ch = chBase + wc * 64 + ni * 16 + rr;
      const float bias = kkPlane ? biasp[ch] : 0.f;
      #pragma unroll
      for (int i = 0; i < 4; ++i) {
        const int row = m0 + wr * 128 + mi * 16 + hs * 4 + i;
        float v = acc[mi][ni][i];
        if (kkPlane) v = 1.f / (1.f + __expf(-(v + bias)));   // uniform branch
        plane[(uint64_t)row * 1024 + ch] = f2h(v);
      }
    }
  }
}

// ---------------- chunked scan, phase A: per-chunk partial (c0=0) + decay product ----------------
__global__ __launch_bounds__(256) void scan_partial_kernel(const u16* __restrict__ xtilP,
                                                           const u16* __restrict__ fP,
                                                           float* __restrict__ cpart,
                                                           float* __restrict__ Pp) {
  int tid = blockIdx.x * 256 + threadIdx.x;       // 262144 = B * NCHUNK * 1024
  int ch = tid & 1023, chunk = (tid >> 10) & (NCHUNK - 1), b = tid >> 14;
  int d = ch >> 9;
  int l = chunk * CHUNK + (d ? CHUNK - 1 : 0);
  int64_t stride = d ? -1024 : 1024;
  uint64_t base = ((uint64_t)b * L_ + l) * 1024 + ch;
  float c = 0.f, P = 1.f;
  #pragma unroll 4
  for (int it = 0; it < CHUNK; ++it) {
    float f  = h2f(fP[base]);
    float xt = h2f(xtilP[base]);
    c = f * c + (1.f - f) * xt;
    P *= f;
    base += stride;
  }
  int o = (b * NCHUNK + chunk) * 1024 + ch;
  cpart[o] = c;
  Pp[o] = P;
}

// ---------------- phase B: sequential combine across chunks (per channel) ----------------
__global__ void scan_combine_kernel(const float* __restrict__ cpart, const float* __restrict__ Pp,
                                    float* __restrict__ cin, float* __restrict__ outc) {
  int tid = blockIdx.x * blockDim.x + threadIdx.x;  // 16384
  int ch = tid & 1023, b = tid >> 10, d = ch >> 9;
  float c = 0.f;
  for (int i = 0; i < NCHUNK; ++i) {
    int chunk = d ? (NCHUNK - 1 - i) : i;
    int o = (b * NCHUNK + chunk) * 1024 + ch;
    cin[o] = c;
    c = cpart[o] + Pp[o] * c;
  }
  outc[ch * B_ + b] = c;   // c.T layout (2H, B)
}

// ---------------- phase C: re-scan each chunk from true c_in, emit h ----------------
__global__ __launch_bounds__(256) void scan_final_kernel(const u16* __restrict__ xb,
                                                         const u16* __restrict__ xtilP,
                                                         const u16* __restrict__ fP,
                                                         const u16* __restrict__ rP,
                                                         const float* __restrict__ cin,
                                                         float* __restrict__ outh) {
  int tid = blockIdx.x * 256 + threadIdx.x;       // 262144
  int ch = tid & 1023, chunk = (tid >> 10) & (NCHUNK - 1), b = tid >> 14;
  int d = ch >> 9;
  int l = chunk * CHUNK + (d ? CHUNK - 1 : 0);
  int64_t stride = d ? -1024 : 1024;
  uint64_t base = ((uint64_t)b * L_ + l) * 1024 + ch;
  float c = cin[(b * NCHUNK + chunk) * 1024 + ch];
  #pragma unroll 2
  for (int it = 0; it < CHUNK; ++it) {
    float f    = h2f(fP[base]);
    float xt   = h2f(xtilP[base]);
    float rr   = h2f(rP[base]);
    float xres = bf2f(xb[base]);
    c = f * c + (1.f - f) * xt;
    float th = 1.f - 2.f / (__expf(2.f * c) + 1.f);   // tanh
    outh[base] = rr * th + (1.f - rr) * xres;
    base += stride;
  }
}

// ---------------- launch ----------------
extern "C" void kernel_launch(void* const* d_in, const int* in_sizes, int n_in,
                              void* d_out, int out_size, void* d_ws, size_t ws_size,
                              hipStream_t stream) {
  const float* x   = (const float*)d_in[0];
  const float* W   = (const float*)d_in[1];
  const float* bfp = (const float*)d_in[2];
  const float* brp = (const float*)d_in[3];

  float* outh = (float*)d_out;
  float* outc = outh + (size_t)B_ * L_ * DIN_;   // after (B, L, 2H)

  // ws layout (262 MiB total):
  u16* xb = (u16*)d_ws;                          // M_*K_ bf16      = 64 MiB (live: phase-C residual)
  u16* Wt = xb + (size_t)M_ * K_;                // NCOL_*K_ bf16   = 6 MiB (dead after GEMM)
  u16* xtilP = Wt + (size_t)NCOL_ * K_;          // M_*1024 fp16    = 64 MiB
  u16* fP    = xtilP + (size_t)M_ * 1024;        // 64 MiB
  u16* rP    = fP    + (size_t)M_ * 1024;        // 64 MiB
  // chunk-scan scratch aliases the dead Wt region (3 MiB <= 6 MiB):
  float* cpart = (float*)Wt;                     // B*NCHUNK*1024 f32 = 1 MiB
  float* Pp    = cpart + (size_t)B_ * NCHUNK * 1024;
  float* cin   = Pp    + (size_t)B_ * NCHUNK * 1024;

  cvt_x_kernel<<<(M_ * K_ / 4) / 256, 256, 0, stream>>>((const float4*)x, (ushort4*)xb);
  transpose_w_kernel<<<dim3(NCOL_ / 32, K_ / 32), dim3(32, 8), 0, stream>>>(W, Wt);
  gemm_u_kernel<<<(M_ / 256) * (NCOL_ / 256), 512, 0, stream>>>(xb, Wt, bfp, brp, xtilP, fP, rP);
  scan_partial_kernel<<<(B_ * NCHUNK * 1024) / 256, 256, 0, stream>>>(xtilP, fP, cpart, Pp);
  scan_combine_kernel<<<(B_ * 2 * H_) / 256, 256, 0, stream>>>(cpart, Pp, cin, outc);
  scan_final_kernel<<<(B_ * NCHUNK * 1024) / 256, 256, 0, stream>>>(xb, xtilP, fP, rP, cin, outh);
}

// Round 7
// 380.104 us; speedup vs baseline: 2.4007x; 1.0118x over previous
//
#include <hip/hip_runtime.h>
#include <stdint.h>

#define B_    16
#define L_    2048
#define DIN_  1024
#define H_    512
#define NCOL_ 3072          // 2 * H * 3
#define M_    (B_ * L_)     // 32768
#define K_    DIN_          // 1024
#define NCHUNK 16
#define CHUNK  128          // L_ / NCHUNK

typedef unsigned short u16;
typedef __bf16 bf16_t;
typedef bf16_t bf16x8 __attribute__((ext_vector_type(8)));
typedef float  f32x4  __attribute__((ext_vector_type(4)));

__device__ __forceinline__ u16 f2bf(float f) {
  union { float f; uint32_t u; } v; v.f = f;
  return (u16)((v.u + 0x7fffu + ((v.u >> 16) & 1u)) >> 16);  // RNE
}
__device__ __forceinline__ float bf2f(u16 b) {
  union { uint32_t u; float f; } v; v.u = ((uint32_t)b) << 16; return v.f;
}
__device__ __forceinline__ u16 f2h(float f) {
  _Float16 h = (_Float16)f; return *(u16*)&h;
}
__device__ __forceinline__ float h2f(u16 b) {
  _Float16 h = *(_Float16*)&b; return (float)h;
}

// ---------------- x f32 -> bf16 ----------------
__global__ void cvt_x_kernel(const float4* __restrict__ x, ushort4* __restrict__ xb) {
  int i = blockIdx.x * blockDim.x + threadIdx.x;   // exact grid, no bounds
  float4 v = x[i];
  ushort4 o;
  o.x = f2bf(v.x); o.y = f2bf(v.y); o.z = f2bf(v.z); o.w = f2bf(v.w);
  xb[i] = o;
}

// ---------------- W (K x N) -> Wt (N' x K) bf16, rows plane-permuted ----------------
// n' = k*1024 + d*512 + h  (so the GEMM N axis is planar: [xtil | f | r])
__global__ void transpose_w_kernel(const float* __restrict__ W, u16* __restrict__ Wt) {
  __shared__ float s[32][33];
  int n0 = blockIdx.x * 32;   // N tile
  int i0 = blockIdx.y * 32;   // K tile
  int tx = threadIdx.x, ty = threadIdx.y;  // (32, 8)
  #pragma unroll
  for (int y = 0; y < 32; y += 8)
    s[ty + y][tx] = W[(uint64_t)(i0 + ty + y) * NCOL_ + n0 + tx];
  __syncthreads();
  #pragma unroll
  for (int y = 0; y < 32; y += 8) {
    int n = n0 + ty + y;
    int kk = n % 3, d = n / 1536, h = (n % 1536) / 3;
    int np = kk * 1024 + d * 512 + h;
    Wt[(uint64_t)np * K_ + i0 + tx] = f2bf(s[tx][ty + y]);
  }
}

// ---------------- 256x256 GEMM, ONE barrier per K-tile, compiler-scheduled ----------------
__device__ __forceinline__ void gload_lds16(const void* g, void* lds) {
  __builtin_amdgcn_global_load_lds(
      (const __attribute__((address_space(1))) uint32_t*)g,
      (__attribute__((address_space(3))) uint32_t*)lds, 16, 0, 0);
}

__device__ __forceinline__ bf16x8 lds_rd(const u16* lds, int byteOff) {
  return __builtin_bit_cast(bf16x8, *(const f32x4*)((const char*)lds + byteOff));
}

// LDS map (bytes), 160 KiB total:
//   A bufs (2): [0, 32768), [32768, 65536)           -- 256 rows x 64 bf16, 128 B/row
//   B bufs (3): 65536 + {0,1,2} * 32768              -- same shape
// T2 swizzle per 128-B row: phys granule g_p = g_l ^ (row&7)
//   write: linear gload_lds dest + pre-swizzled GLOBAL source granule
//   read:  byte ^= (row&7)<<4  -> conflict-free ds_read_b128
//
// R7 schedule: free-running tile, ONE raw barrier per K-tile boundary.
//   per tile t: issue stageA(t+1)/stageB(t+2); read bF + per-quadrant aF;
//   MFMAs interleave with reads via compiler-emitted counted lgkmcnt
//   (no intra-tile barriers, no lgkmcnt(0) drains, no order pinning).
//   Correctness: RAW (buffer t staged before reads) = vmcnt(4)+boundary
//   barrier of t-1; WAR (re-staging buffer read at t-1) = each wave's
//   t-1 reads complete before its last t-1 MFMA issues (compiler lgkm
//   waits), which precedes the boundary barrier; staging issued after.
__global__ __launch_bounds__(512, 2) void gemm_u_kernel(const u16* __restrict__ A,
                                                        const u16* __restrict__ Bt,
                                                        const float* __restrict__ bfp,
                                                        const float* __restrict__ brp,
                                                        u16* __restrict__ xtilP,
                                                        u16* __restrict__ fP,
                                                        u16* __restrict__ rP) {
  __shared__ __align__(16) u16 lds[81920];       // 160 KiB

  // Block->tile mapping (R5): XCD-chunked M (16 bm per XCD), bm-fast within XCD.
  const int bid = blockIdx.x;
  const int xcd = bid & 7;
  const int li  = bid >> 3;                     // 0..191 within XCD
  const int bm  = xcd * 16 + (li & 15);
  const int bn  = li >> 4;                      // 0..11
  const int m0 = bm * 256, n0 = bn * 256;

  const int tid  = threadIdx.x;
  const int w    = tid >> 6, lane = tid & 63;
  const int wr   = w >> 2, wc = w & 3;          // 2M x 4N waves; per-wave out 128x64
  const int rr   = lane & 15, hs = lane >> 4;
  const int swzRd = (rr & 7) << 4;
  const int hsOff = hs * 16;

  // staging: round (h,j), wave w writes LDS [buf + h*16384 + j*8192 + w*1024 + lane*16]
  //  -> row = h*128 + j*64 + w*8 + (lane>>3); granule = lane&7; src granule = (lane&7)^(row&7)
  const int rStage = w * 8 + (lane >> 3);
  const int sCol   = ((lane & 7) ^ ((lane >> 3) & 7)) * 8;
  const int ldsChunk = w * 1024;

  f32x4 acc[8][4] = {};

  auto stageA = [&](int bufBase, int kt) {
    #pragma unroll
    for (int h = 0; h < 2; ++h)
      #pragma unroll
      for (int j = 0; j < 2; ++j)
        gload_lds16(A + (uint64_t)(m0 + h * 128 + j * 64 + rStage) * K_ + kt + sCol,
                    (char*)lds + bufBase + h * 16384 + j * 8192 + ldsChunk);
  };
  auto stageB = [&](int bufBase, int kt) {
    #pragma unroll
    for (int h = 0; h < 2; ++h)
      #pragma unroll
      for (int j = 0; j < 2; ++j)
        gload_lds16(Bt + (uint64_t)(n0 + h * 128 + j * 64 + rStage) * K_ + kt + sCol,
                    (char*)lds + bufBase + h * 16384 + j * 8192 + ldsChunk);
  };

  // prologue: A(0)->Ab0, B(0)->Bb0, B(1)->Bb1; require A0,B0; leave B1 in flight
  stageA(0, 0);
  stageB(65536, 0);
  stageB(65536 + 32768, 64);
  asm volatile("s_waitcnt vmcnt(4)" ::: "memory");
  __builtin_amdgcn_sched_barrier(0);
  __builtin_amdgcn_s_barrier();

  const int aHalfBase = wr * 16384;             // within A buf
  const int bQuart    = (wc >> 1) * 16384;      // within B buf
  const int rowB0     = (wc & 1) * 64;

  int b3 = 0;                                    // t % 3
  #pragma unroll 1
  for (int t = 0; t < 16; ++t) {
    const int curA = (t & 1) << 15;
    const int curB = 65536 + b3 * 32768;
    const int b3n2 = (b3 >= 1) ? (b3 - 1) : 2;   // (t+2) % 3

    // issue next-tile staging first (VMEM latency covered by this tile's compute)
    if (t < 15) stageA((~t & 1) << 15, (t + 1) * 64);
    if (t < 14) stageB(65536 + b3n2 * 32768, (t + 2) * 64);

    // B fragments for the whole tile
    bf16x8 bF[4][2];
    #pragma unroll
    for (int ni = 0; ni < 4; ++ni)
      #pragma unroll
      for (int ks = 0; ks < 2; ++ks)
        bF[ni][ks] = lds_rd(lds, curB + bQuart + (rowB0 + ni * 16 + rr) * 128 + ((ks * 64 + hsOff) ^ swzRd));

    // quadrants: reads + MFMAs, compiler-interleaved (counted lgkm waits)
    #pragma unroll
    for (int q = 0; q < 4; ++q) {
      bf16x8 a0[2], a1[2];
      #pragma unroll
      for (int ks = 0; ks < 2; ++ks) {
        a0[ks] = lds_rd(lds, curA + aHalfBase + ((2 * q) * 16 + rr) * 128 + ((ks * 64 + hsOff) ^ swzRd));
        a1[ks] = lds_rd(lds, curA + aHalfBase + ((2 * q + 1) * 16 + rr) * 128 + ((ks * 64 + hsOff) ^ swzRd));
      }
      #pragma unroll
      for (int ni = 0; ni < 4; ++ni)
        #pragma unroll
        for (int ks = 0; ks < 2; ++ks) {
          acc[2 * q][ni]     = __builtin_amdgcn_mfma_f32_16x16x32_bf16(a0[ks], bF[ni][ks], acc[2 * q][ni], 0, 0, 0);
          acc[2 * q + 1][ni] = __builtin_amdgcn_mfma_f32_16x16x32_bf16(a1[ks], bF[ni][ks], acc[2 * q + 1][ni], 0, 0, 0);
        }
    }

    // tile boundary: A(t+1),B(t+1) must be LDS-resident for everyone after the
    // barrier; B(t+2) (4 newest loads) stays in flight across it.
    if (t < 14) {
      asm volatile("s_waitcnt vmcnt(4)" ::: "memory");
      __builtin_amdgcn_sched_barrier(0);
    } else if (t == 14) {
      asm volatile("s_waitcnt vmcnt(0)" ::: "memory");
      __builtin_amdgcn_sched_barrier(0);
    }
    if (t < 15) __builtin_amdgcn_s_barrier();

    b3 = (b3 + 1 == 3) ? 0 : b3 + 1;
  }

  // epilogue: C/D col = lane&15, row = (lane>>4)*4 + i  [m89-verified].
  // N planar: plane kk = n0>>10 block-uniform; ch = (n0&1023) + incol.
  const int kkPlane = n0 >> 10;             // 0: xtil, 1: f, 2: r
  const int chBase  = n0 & 1023;
  u16* plane = (kkPlane == 0) ? xtilP : (kkPlane == 1 ? fP : rP);
  const float* biasp = (kkPlane == 1) ? bfp : brp;
  #pragma unroll
  for (int mi = 0; mi < 8; ++mi) {
    #pragma unroll
    for (int ni = 0; ni < 4; ++ni) {
      const int ch = chBase + wc * 64 + ni * 16 + rr;
      const float bias = kkPlane ? biasp[ch] : 0.f;
      #pragma unroll
      for (int i = 0; i < 4; ++i) {
        const int row = m0 + wr * 128 + mi * 16 + hs * 4 + i;
        float v = acc[mi][ni][i];
        if (kkPlane) v = 1.f / (1.f + __expf(-(v + bias)));   // uniform branch
        plane[(uint64_t)row * 1024 + ch] = f2h(v);
      }
    }
  }
}

// ---------------- chunked scan, phase A: per-chunk partial (c0=0) + decay product ----------------
__global__ __launch_bounds__(256) void scan_partial_kernel(const u16* __restrict__ xtilP,
                                                           const u16* __restrict__ fP,
                                                           float* __restrict__ cpart,
                                                           float* __restrict__ Pp) {
  int tid = blockIdx.x * 256 + threadIdx.x;       // 262144 = B * NCHUNK * 1024
  int ch = tid & 1023, chunk = (tid >> 10) & (NCHUNK - 1), b = tid >> 14;
  int d = ch >> 9;
  int l = chunk * CHUNK + (d ? CHUNK - 1 : 0);
  int64_t stride = d ? -1024 : 1024;
  uint64_t base = ((uint64_t)b * L_ + l) * 1024 + ch;
  float c = 0.f, P = 1.f;
  #pragma unroll 4
  for (int it = 0; it < CHUNK; ++it) {
    float f  = h2f(fP[base]);
    float xt = h2f(xtilP[base]);
    c = f * c + (1.f - f) * xt;
    P *= f;
    base += stride;
  }
  int o = (b * NCHUNK + chunk) * 1024 + ch;
  cpart[o] = c;
  Pp[o] = P;
}

// ---------------- phase B: sequential combine across chunks (per channel) ----------------
__global__ void scan_combine_kernel(const float* __restrict__ cpart, const float* __restrict__ Pp,
                                    float* __restrict__ cin, float* __restrict__ outc) {
  int tid = blockIdx.x * blockDim.x + threadIdx.x;  // 16384
  int ch = tid & 1023, b = tid >> 10, d = ch >> 9;
  float c = 0.f;
  for (int i = 0; i < NCHUNK; ++i) {
    int chunk = d ? (NCHUNK - 1 - i) : i;
    int o = (b * NCHUNK + chunk) * 1024 + ch;
    cin[o] = c;
    c = cpart[o] + Pp[o] * c;
  }
  outc[ch * B_ + b] = c;   // c.T layout (2H, B)
}

// ---------------- phase C: re-scan each chunk from true c_in, emit h ----------------
__global__ __launch_bounds__(256) void scan_final_kernel(const u16* __restrict__ xb,
                                                         const u16* __restrict__ xtilP,
                                                         const u16* __restrict__ fP,
                                                         const u16* __restrict__ rP,
                                                         const float* __restrict__ cin,
                                                         float* __restrict__ outh) {
  int tid = blockIdx.x * 256 + threadIdx.x;       // 262144
  int ch = tid & 1023, chunk = (tid >> 10) & (NCHUNK - 1), b = tid >> 14;
  int d = ch >> 9;
  int l = chunk * CHUNK + (d ? CHUNK - 1 : 0);
  int64_t stride = d ? -1024 : 1024;
  uint64_t base = ((uint64_t)b * L_ + l) * 1024 + ch;
  float c = cin[(b * NCHUNK + chunk) * 1024 + ch];
  #pragma unroll 2
  for (int it = 0; it < CHUNK; ++it) {
    float f    = h2f(fP[base]);
    float xt   = h2f(xtilP[base]);
    float rr   = h2f(rP[base]);
    float xres = bf2f(xb[base]);
    c = f * c + (1.f - f) * xt;
    float th = 1.f - 2.f / (__expf(2.f * c) + 1.f);   // tanh
    outh[base] = rr * th + (1.f - rr) * xres;
    base += stride;
  }
}

// ---------------- launch ----------------
extern "C" void kernel_launch(void* const* d_in, const int* in_sizes, int n_in,
                              void* d_out, int out_size, void* d_ws, size_t ws_size,
                              hipStream_t stream) {
  const float* x   = (const float*)d_in[0];
  const float* W   = (const float*)d_in[1];
  const float* bfp = (const float*)d_in[2];
  const float* brp = (const float*)d_in[3];

  float* outh = (float*)d_out;
  float* outc = outh + (size_t)B_ * L_ * DIN_;   // after (B, L, 2H)

  // ws layout (262 MiB total):
  u16* xb = (u16*)d_ws;                          // M_*K_ bf16      = 64 MiB (live: phase-C residual)
  u16* Wt = xb + (size_t)M_ * K_;                // NCOL_*K_ bf16   = 6 MiB (dead after GEMM)
  u16* xtilP = Wt + (size_t)NCOL_ * K_;          // M_*1024 fp16    = 64 MiB
  u16* fP    = xtilP + (size_t)M_ * 1024;        // 64 MiB
  u16* rP    = fP    + (size_t)M_ * 1024;        // 64 MiB
  // chunk-scan scratch aliases the dead Wt region (3 MiB <= 6 MiB):
  float* cpart = (float*)Wt;                     // B*NCHUNK*1024 f32 = 1 MiB
  float* Pp    = cpart + (size_t)B_ * NCHUNK * 1024;
  float* cin   = Pp    + (size_t)B_ * NCHUNK * 1024;

  cvt_x_kernel<<<(M_ * K_ / 4) / 256, 256, 0, stream>>>((const float4*)x, (ushort4*)xb);
  transpose_w_kernel<<<dim3(NCOL_ / 32, K_ / 32), dim3(32, 8), 0, stream>>>(W, Wt);
  gemm_u_kernel<<<(M_ / 256) * (NCOL_ / 256), 512, 0, stream>>>(xb, Wt, bfp, brp, xtilP, fP, rP);
  scan_partial_kernel<<<(B_ * NCHUNK * 1024) / 256, 256, 0, stream>>>(xtilP, fP, cpart, Pp);
  scan_combine_kernel<<<(B_ * 2 * H_) / 256, 256, 0, stream>>>(cpart, Pp, cin, outc);
  scan_final_kernel<<<(B_ * NCHUNK * 1024) / 256, 256, 0, stream>>>(xb, xtilP, fP, rP, cin, outh);
}